// Round 1
// baseline (3634.205 us; speedup 1.0000x reference)
//
#include <hip/hip_runtime.h>
#include <hip/hip_bf16.h>

// Problem constants
#define BATCH 2048
#define HID 256
#define COND 128
#define NCH 64
#define MAXLEN 128
#define RDIM 256

// Workspace float offsets
#define WCAT_OFF 0        // [256][256 units][4 gates] combined (r,z share Wih+Whh; i_n; h_n)
#define WHH0_OFF 262144   // [256][256][4] step-0 matrix (Whh_r, Whh_z, Whh_n, 0)
#define WLH_OFF  524288   // [384][256] latent_to_hidden transposed
#define WOUT_OFF 622592   // [256][64] output weights k-major
#define BCAT_OFF 638976   // [256][4] biases per unit (t>=1)
#define BCAT0_OFF 640000  // [256][4] biases per unit (t==0)

__global__ void prep_kernel(const float* __restrict__ W_lh,
                            const float* __restrict__ W_ih, const float* __restrict__ W_hh,
                            const float* __restrict__ b_ih, const float* __restrict__ b_hh,
                            const float* __restrict__ W_out, float* __restrict__ ws) {
    int gid = blockIdx.x * blockDim.x + threadIdx.x;   // 0..98303
    if (gid < 384 * 256) {
        int k = gid >> 8, u = gid & 255;
        ws[WLH_OFF + gid] = W_lh[u * 384 + k];
    }
    if (gid < 65536) {
        int k = gid >> 8, u = gid & 255;
        float ir = W_ih[u * 256 + k], iz = W_ih[(256 + u) * 256 + k], inw = W_ih[(512 + u) * 256 + k];
        float hr = W_hh[u * 256 + k], hz = W_hh[(256 + u) * 256 + k], hnw = W_hh[(512 + u) * 256 + k];
        int base = WCAT_OFF + k * 1024 + u * 4;
        ws[base + 0] = ir + hr; ws[base + 1] = iz + hz; ws[base + 2] = inw; ws[base + 3] = hnw;
        base = WHH0_OFF + k * 1024 + u * 4;
        ws[base + 0] = hr; ws[base + 1] = hz; ws[base + 2] = hnw; ws[base + 3] = 0.0f;
    }
    if (gid < 16384) {
        int k = gid >> 6, o = gid & 63;
        ws[WOUT_OFF + k * 64 + o] = W_out[o * 256 + k];
    }
    if (gid < 256) {
        int u = gid;
        float bir = b_ih[u], biz = b_ih[256 + u];
        float bhr = b_hh[u], bhz = b_hh[256 + u], bhn = b_hh[512 + u];
        int base = BCAT_OFF + u * 4;
        ws[base + 0] = bir + bhr; ws[base + 1] = biz + bhz; ws[base + 2] = b_ih[512 + u]; ws[base + 3] = bhn;
        base = BCAT0_OFF + u * 4;
        ws[base + 0] = bir + bhr; ws[base + 1] = biz + bhz; ws[base + 2] = bhn; ws[base + 3] = 0.0f;
    }
}

__device__ __forceinline__ float sigm(float x)   { return 1.0f / (1.0f + __expf(-x)); }
__device__ __forceinline__ float tanh_f(float x) { return 1.0f - 2.0f / (1.0f + __expf(2.0f * x)); }

// 256 workgroups x 256 threads; wg owns 8 batch rows; thread t owns hidden unit t.
__global__ __launch_bounds__(256)
void gru_persist(const float* __restrict__ z, const float* __restrict__ xc,
                 const float* __restrict__ b_lh, const float* __restrict__ b_ih,
                 const float* __restrict__ b_out_g,
                 const float* __restrict__ ws, float* __restrict__ out) {
    __shared__ __align__(16) float lds_h[8 * 256];     // hidden state, 8 rows
    __shared__ __align__(16) float lds_w[256 * 64];    // zc staging, then Wout [k][o]

    const int t  = threadIdx.x;        // hidden unit owned by this thread
    const int b0 = blockIdx.x * 8;     // first batch row

    // ---- stage zc = [z | x_cond] rows b0..b0+7 into lds_w as [i][384]
    for (int idx = t; idx < 8 * 384; idx += 256) {
        int i = idx / 384, k = idx - i * 384;
        float v = (k < 256) ? z[(b0 + i) * 256 + k] : xc[(b0 + i) * 128 + (k - 256)];
        lds_w[i * 384 + k] = v;
    }
    __syncthreads();

    // ---- h0 = zc @ W_lh^T + b_lh  (thread t -> column t, 8 rows)
    float h_own[8];
    {
        float acc[8];
        float blh = b_lh[t];
#pragma unroll
        for (int i = 0; i < 8; i++) acc[i] = blh;
        const float* Wlh = ws + WLH_OFF;
        for (int k4 = 0; k4 < 96; ++k4) {
            int k = k4 * 4;
            float w0 = Wlh[(k + 0) * 256 + t];
            float w1 = Wlh[(k + 1) * 256 + t];
            float w2 = Wlh[(k + 2) * 256 + t];
            float w3 = Wlh[(k + 3) * 256 + t];
#pragma unroll
            for (int i = 0; i < 8; i++) {
                const float4 hv = *(const float4*)&lds_w[i * 384 + k];
                acc[i] += hv.x * w0 + hv.y * w1 + hv.z * w2 + hv.w * w3;
            }
        }
#pragma unroll
        for (int i = 0; i < 8; i++) { h_own[i] = acc[i]; lds_h[i * 256 + t] = acc[i]; }
    }
    __syncthreads();   // zc reads done, h0 visible

    // ---- stage Wout [k][64] into lds_w
    {
        const float* Wo = ws + WOUT_OFF;
        for (int idx = t; idx < 16384; idx += 256) lds_w[idx] = Wo[idx];
    }
    __syncthreads();

    const float4* Wcat = (const float4*)(ws + WCAT_OFF);   // [k][unit] of float4 gates
    const float4* Whh0 = (const float4*)(ws + WHH0_OFF);
    const float4 bc1 = ((const float4*)(ws + BCAT_OFF))[t];
    const float4 bc0 = ((const float4*)(ws + BCAT0_OFF))[t];
    const float bin_c = b_ih[512 + t];
    const int olane = t & 63, rg = t >> 6;
    const float bout = b_out_g[olane];
    float* outp = out + (long)b0 * MAXLEN * NCH;

    for (int st = 0; st < MAXLEN; ++st) {
        const float4* Wp = (st == 0) ? Whh0 : Wcat;
        const float4 bc = (st == 0) ? bc0 : bc1;
        float ax[8], ay[8], az[8], aw[8];
#pragma unroll
        for (int i = 0; i < 8; i++) { ax[i] = bc.x; ay[i] = bc.y; az[i] = bc.z; aw[i] = bc.w; }

#pragma unroll 2
        for (int k4 = 0; k4 < 64; ++k4) {
            int k = k4 * 4;
            float4 w0 = Wp[(k + 0) * 256 + t];
            float4 w1 = Wp[(k + 1) * 256 + t];
            float4 w2 = Wp[(k + 2) * 256 + t];
            float4 w3 = Wp[(k + 3) * 256 + t];
#pragma unroll
            for (int i = 0; i < 8; i++) {
                const float4 hv = *(const float4*)&lds_h[i * 256 + k];
                ax[i] += hv.x * w0.x; ay[i] += hv.x * w0.y; az[i] += hv.x * w0.z; aw[i] += hv.x * w0.w;
                ax[i] += hv.y * w1.x; ay[i] += hv.y * w1.y; az[i] += hv.y * w1.z; aw[i] += hv.y * w1.w;
                ax[i] += hv.z * w2.x; ay[i] += hv.z * w2.y; az[i] += hv.z * w2.z; aw[i] += hv.z * w2.w;
                ax[i] += hv.w * w3.x; ay[i] += hv.w * w3.y; az[i] += hv.w * w3.z; aw[i] += hv.w * w3.w;
            }
        }

        // epilogue: gates -> hn (thread-local, no exchange needed)
        float hn_[8];
        if (st == 0) {
#pragma unroll
            for (int i = 0; i < 8; i++) {
                float r = sigm(ax[i]); float uu = sigm(ay[i]);
                float n = tanh_f(bin_c + r * az[i]);       // i_n = b_ih_n const (x=0)
                hn_[i] = (1.0f - uu) * n + uu * h_own[i];
            }
        } else {
#pragma unroll
            for (int i = 0; i < 8; i++) {
                float r = sigm(ax[i]); float uu = sigm(ay[i]);
                float n = tanh_f(az[i] + r * aw[i]);
                hn_[i] = (1.0f - uu) * n + uu * h_own[i];
            }
        }
        __syncthreads();   // all lds_h readers (this GEMM + prev logits) done
#pragma unroll
        for (int i = 0; i < 8; i++) { lds_h[i * 256 + t] = hn_[i]; h_own[i] = hn_[i]; }
        __syncthreads();   // new h visible

        // logits = hn @ Wout^T + b_out ; thread handles (o = t&63) for rows 2rg, 2rg+1
        {
            float l0 = bout, l1 = bout;
            const int r0 = 2 * rg, r1 = 2 * rg + 1;
            for (int k4 = 0; k4 < 64; ++k4) {
                int k = k4 * 4;
                const float4 h0v = *(const float4*)&lds_h[r0 * 256 + k];
                const float4 h1v = *(const float4*)&lds_h[r1 * 256 + k];
                float wq0 = lds_w[(k + 0) * 64 + olane];
                float wq1 = lds_w[(k + 1) * 64 + olane];
                float wq2 = lds_w[(k + 2) * 64 + olane];
                float wq3 = lds_w[(k + 3) * 64 + olane];
                l0 += h0v.x * wq0 + h0v.y * wq1 + h0v.z * wq2 + h0v.w * wq3;
                l1 += h1v.x * wq0 + h1v.y * wq1 + h1v.z * wq2 + h1v.w * wq3;
            }
            outp[(long)r0 * MAXLEN * NCH + st * NCH + olane] = l0;
            outp[(long)r1 * MAXLEN * NCH + st * NCH + olane] = l1;
        }
    }
}

extern "C" void kernel_launch(void* const* d_in, const int* in_sizes, int n_in,
                              void* d_out, int out_size, void* d_ws, size_t ws_size,
                              hipStream_t stream) {
    const float* z     = (const float*)d_in[0];
    const float* xcond = (const float*)d_in[1];
    const float* W_lh  = (const float*)d_in[2];
    const float* b_lh  = (const float*)d_in[3];
    const float* W_ih  = (const float*)d_in[4];
    const float* W_hh  = (const float*)d_in[5];
    const float* b_ih  = (const float*)d_in[6];
    const float* b_hh  = (const float*)d_in[7];
    const float* W_out = (const float*)d_in[8];
    const float* b_out = (const float*)d_in[9];
    float* out = (float*)d_out;
    float* ws  = (float*)d_ws;

    hipLaunchKernelGGL(prep_kernel, dim3(384), dim3(256), 0, stream,
                       W_lh, W_ih, W_hh, b_ih, b_hh, W_out, ws);
    hipLaunchKernelGGL(gru_persist, dim3(256), dim3(256), 0, stream,
                       z, xcond, b_lh, b_ih, b_out, ws, out);
}